// Round 1
// baseline (8988.074 us; speedup 1.0000x reference)
//
#include <hip/hip_runtime.h>

#define B_ 2
#define S_ 1024
#define E_ 1024
#define H_ 16
#define DK_ 64
#define F_ 4096
#define L_ 4
#define V_ 32000
#define BS_ (B_*S_)   // 2048

typedef short bf16x8 __attribute__((ext_vector_type(8)));
typedef float f32x4 __attribute__((ext_vector_type(4)));

__device__ inline unsigned short f2b(float x) {
  union { float f; unsigned u; } un; un.f = x;
  unsigned r = un.u + 0x7fffu + ((un.u >> 16) & 1u);
  return (unsigned short)(r >> 16);
}
__device__ inline float b2f(unsigned short b) {
  union { unsigned u; float f; } un; un.u = ((unsigned)b) << 16;
  return un.f;
}

// Detect whether float inputs are stored as bf16 (flag=1) or f32 (flag=0).
// mlp_norm_w is all-ones: f32 word = 0x3F800000, bf16 pair = 0x3F803F80.
__global__ void detect_kernel(const unsigned* __restrict__ normw, int* __restrict__ flag) {
  if (threadIdx.x == 0) *flag = (normw[0] == 0x3F800000u) ? 0 : 1;
}

__global__ __launch_bounds__(256) void embed_kernel(
    const int* __restrict__ tokens, const void* __restrict__ table,
    float* __restrict__ emb, const int* __restrict__ flagp)
{
  const int flag = *flagp;
  const int row = blockIdx.x;           // (b,s) 0..2047
  const int tok = tokens[row];
  const int tid = threadIdx.x;
  #pragma unroll
  for (int c = 0; c < 4; c++) {
    const int i = tid + 256 * c;
    float v;
    if (flag) v = b2f(((const unsigned short*)table)[(long)tok * E_ + i]);
    else      v = ((const float*)table)[(long)tok * E_ + i];
    emb[(long)row * E_ + i] = v;
  }
}

// C[M,N] = A[M,K] (f32, staged->bf16) x B[K,N] (bf16 or f32 weights)
// amode: 0 = A row-major [M,K]; 1 = A gathered from bhsd layout (K index = h*64+d)
// B element (kk,nn) at: bOff + (nn>>6)*bsH + kk*bsK + (nn&63)
// cmode: 0 = C[row*N+col] = v (+resid);  1 = scatter to bhsk: C[(((b*H+h)*S)+s)*64+dk]
//        2 = logits: v += bias[col]; store (bf16|f32 per flag) to outb
//        3 = C[idx] = resid[idx] * elu(v)   (fused up * elu(gate))
__global__ __launch_bounds__(256) void gemm_kernel(
    const float* __restrict__ A, const void* __restrict__ Bw,
    float* __restrict__ C, const float* __restrict__ resid,
    const void* __restrict__ bias, void* __restrict__ outb,
    const int* __restrict__ flagp,
    int M, int N, int K, int amode, long bOff, long bsH, long bsK, int cmode)
{
  const int flag = *flagp;
  __shared__ unsigned short As[64][40];   // [m][k] bf16, stride 40 to dodge conflicts
  __shared__ unsigned short Bs[64][40];   // [n][k] bf16 (transposed at staging)
  const int tid = threadIdx.x;
  const int m0 = blockIdx.y * 64, n0 = blockIdx.x * 64;
  f32x4 acc[2][2] = {};
  const int arow = tid >> 2, acol = (tid & 3) * 8;   // A: 64 rows x 32 k, 8 f32/thread
  const int brow = tid >> 3, bcol = (tid & 7) * 8;   // B: 32 k x 64 n, 8 elems/thread
  const int w = tid >> 6, lane = tid & 63;
  const int wm = (w & 1) * 32, wn = (w >> 1) * 32;
  const int lr = lane & 15, quad = lane >> 4;

  for (int k0 = 0; k0 < K; k0 += 32) {
    { // ---- stage A tile ----
      const int mm = m0 + arow;
      const int kk = k0 + acol;
      long aoff;
      if (amode == 0) aoff = (long)mm * K + kk;
      else {
        const int bb = mm >> 10, ss = mm & 1023, hh = kk >> 6, dd = kk & 63;
        aoff = ((((long)bb * H_ + hh) * S_) + ss) * 64 + dd;
      }
      const float4* ap = (const float4*)(A + aoff);
      const float4 v0 = ap[0], v1 = ap[1];
      unsigned short* dst = &As[arow][acol];
      dst[0]=f2b(v0.x); dst[1]=f2b(v0.y); dst[2]=f2b(v0.z); dst[3]=f2b(v0.w);
      dst[4]=f2b(v1.x); dst[5]=f2b(v1.y); dst[6]=f2b(v1.z); dst[7]=f2b(v1.w);
    }
    { // ---- stage B tile (transpose into [n][k]) ----
      const int kk = k0 + brow;
      const long nn = n0 + bcol;
      const long boff = bOff + (nn >> 6) * bsH + (long)kk * bsK + (nn & 63);
      unsigned short bv[8];
      if (flag) {
        const uint4 raw = *(const uint4*)((const unsigned short*)Bw + boff);
        bv[0]=raw.x&0xffffu; bv[1]=raw.x>>16; bv[2]=raw.y&0xffffu; bv[3]=raw.y>>16;
        bv[4]=raw.z&0xffffu; bv[5]=raw.z>>16; bv[6]=raw.w&0xffffu; bv[7]=raw.w>>16;
      } else {
        const float4* bp = (const float4*)((const float*)Bw + boff);
        const float4 f0 = bp[0], f1 = bp[1];
        bv[0]=f2b(f0.x); bv[1]=f2b(f0.y); bv[2]=f2b(f0.z); bv[3]=f2b(f0.w);
        bv[4]=f2b(f1.x); bv[5]=f2b(f1.y); bv[6]=f2b(f1.z); bv[7]=f2b(f1.w);
      }
      #pragma unroll
      for (int j = 0; j < 8; j++) Bs[bcol + j][brow] = bv[j];
    }
    __syncthreads();
    const bf16x8 af0 = *(const bf16x8*)&As[wm + lr][quad * 8];
    const bf16x8 af1 = *(const bf16x8*)&As[wm + 16 + lr][quad * 8];
    const bf16x8 bg0 = *(const bf16x8*)&Bs[wn + lr][quad * 8];
    const bf16x8 bg1 = *(const bf16x8*)&Bs[wn + 16 + lr][quad * 8];
    acc[0][0] = __builtin_amdgcn_mfma_f32_16x16x32_bf16(af0, bg0, acc[0][0], 0, 0, 0);
    acc[0][1] = __builtin_amdgcn_mfma_f32_16x16x32_bf16(af0, bg1, acc[0][1], 0, 0, 0);
    acc[1][0] = __builtin_amdgcn_mfma_f32_16x16x32_bf16(af1, bg0, acc[1][0], 0, 0, 0);
    acc[1][1] = __builtin_amdgcn_mfma_f32_16x16x32_bf16(af1, bg1, acc[1][1], 0, 0, 0);
    __syncthreads();
  }
  // epilogue: C/D layout col=lane&15, row=quad*4+reg  [HW-verified]
  #pragma unroll
  for (int i = 0; i < 2; i++)
    #pragma unroll
    for (int j = 0; j < 2; j++)
      #pragma unroll
      for (int r = 0; r < 4; r++) {
        const int row = m0 + wm + i * 16 + quad * 4 + r;
        const int col = n0 + wn + j * 16 + lr;
        float v = acc[i][j][r];
        if (cmode == 0) {
          const long idx = (long)row * N + col;
          if (resid) v += resid[idx];
          C[idx] = v;
        } else if (cmode == 1) {
          const int bb = row >> 10, ss = row & 1023, hh = col >> 6, dd = col & 63;
          C[((((long)bb * H_ + hh) * S_) + ss) * 64 + dd] = v;
        } else if (cmode == 2) {
          const float bvl = flag ? b2f(((const unsigned short*)bias)[col])
                                 : ((const float*)bias)[col];
          v += bvl;
          const long idx = (long)row * N + col;
          if (flag) ((unsigned short*)outb)[idx] = f2b(v);
          else      ((float*)outb)[idx] = v;
        } else {
          const long idx = (long)row * N + col;
          const float g = (v > 0.0f) ? v : expm1f(v);
          C[idx] = resid[idx] * g;
        }
      }
}

// In-place RoPE on q and k (bhsk layout). One wave per row of 64.
__global__ __launch_bounds__(64) void rope_kernel(float* __restrict__ q, float* __restrict__ k) {
  const int idx = blockIdx.x;                 // 0 .. 2*B*H*S-1
  float* buf = (idx < B_ * H_ * S_) ? q : k;
  const int r = (idx < B_ * H_ * S_) ? idx : idx - B_ * H_ * S_;
  const int s = r & (S_ - 1);
  const int i = threadIdx.x;                  // 0..63
  float* xr = buf + (long)r * 64;
  const float x  = xr[i];
  const float xs = xr[(i + 32) & 63];         // swapped half
  const int im = i & 31;
  const float theta = expf(-(float)im * 0.28782313662425575f);  // ln(10000)/32
  const float ang = (float)s * theta;
  const float sign = (i < 32) ? -1.0f : 1.0f;
  xr[i] = cosf(ang) * x + sign * sinf(ang) * xs;
}

// One block per (s, b*h): scores row in LDS, block softmax, PV.
__global__ __launch_bounds__(256) void attn_kernel(
    const float* __restrict__ q, const float* __restrict__ k,
    const float* __restrict__ v, float* __restrict__ o)
{
  const int s = blockIdx.x;
  const int bh = blockIdx.y;
  const int tid = threadIdx.x;
  const float* K = k + (long)bh * S_ * 64;
  const float* V = v + (long)bh * S_ * 64;
  __shared__ float qs[64];
  __shared__ float sc[S_];
  __shared__ float redm[4], reds[4], osum[4][64];
  if (tid < 64) qs[tid] = q[((long)bh * S_ + s) * 64 + tid];
  __syncthreads();
  float lmax = -__builtin_inff();
  for (int t = tid; t < S_; t += 256) {
    float d = -__builtin_inff();
    if (t <= s) {
      const float4* kr = (const float4*)(K + (long)t * 64);
      float a = 0.0f;
      #pragma unroll
      for (int j = 0; j < 16; j++) {
        const float4 kv = kr[j];
        a += kv.x * qs[4*j] + kv.y * qs[4*j+1] + kv.z * qs[4*j+2] + kv.w * qs[4*j+3];
      }
      d = a * 0.125f;                          // 1/sqrt(64)
    }
    sc[t] = d;
    lmax = fmaxf(lmax, d);
  }
  #pragma unroll
  for (int off = 32; off > 0; off >>= 1) lmax = fmaxf(lmax, __shfl_down(lmax, off, 64));
  if ((tid & 63) == 0) redm[tid >> 6] = lmax;
  __syncthreads();
  const float mx = fmaxf(fmaxf(redm[0], redm[1]), fmaxf(redm[2], redm[3]));
  float lsum = 0.0f;
  for (int t = tid; t < S_; t += 256) {
    const float e = expf(sc[t] - mx);          // exp(-inf)=0 handles mask
    sc[t] = e;
    lsum += e;
  }
  #pragma unroll
  for (int off = 32; off > 0; off >>= 1) lsum += __shfl_down(lsum, off, 64);
  if ((tid & 63) == 0) reds[tid >> 6] = lsum;
  __syncthreads();
  const float tot = reds[0] + reds[1] + reds[2] + reds[3];
  const int d = tid & 63, g = tid >> 6;
  const int tend = min(S_, s + 1);
  float accv = 0.0f;
  const int t1 = min((g + 1) * 256, tend);
  for (int t = g * 256; t < t1; t++) accv += sc[t] * V[(long)t * 64 + d];
  osum[g][d] = accv;
  __syncthreads();
  if (tid < 64) {
    const float r = (osum[0][tid] + osum[1][tid] + osum[2][tid] + osum[3][tid]) / tot;
    o[((long)bh * S_ + s) * 64 + tid] = r;
  }
}

__global__ __launch_bounds__(256) void rmsnorm_kernel(
    const float* __restrict__ x, const void* __restrict__ wsrc,
    float* __restrict__ y, const int* __restrict__ flagp, long wOff)
{
  const int flag = *flagp;
  const int row = blockIdx.x;
  const int tid = threadIdx.x;
  const float* xr = x + (long)row * E_;
  float ss = 0.0f;
  #pragma unroll
  for (int c = 0; c < 4; c++) { const float vv = xr[tid + 256 * c]; ss += vv * vv; }
  __shared__ float red[4];
  #pragma unroll
  for (int off = 32; off > 0; off >>= 1) ss += __shfl_down(ss, off, 64);
  if ((tid & 63) == 0) red[tid >> 6] = ss;
  __syncthreads();
  const float tot = red[0] + red[1] + red[2] + red[3];
  const float scale = rsqrtf(tot * (1.0f / E_) + 1.1920929e-7f);
  #pragma unroll
  for (int c = 0; c < 4; c++) {
    const int i = tid + 256 * c;
    const float wv = flag ? b2f(((const unsigned short*)wsrc)[wOff + i])
                          : ((const float*)wsrc)[wOff + i];
    y[(long)row * E_ + i] = xr[i] * scale * wv;
  }
}

extern "C" void kernel_launch(void* const* d_in, const int* in_sizes, int n_in,
                              void* d_out, int out_size, void* d_ws, size_t ws_size,
                              hipStream_t stream) {
  const int* tokens = (const int*)d_in[0];
  const void* table = d_in[1];
  const void* Wq = d_in[2];
  const void* Wk = d_in[3];
  const void* Wv = d_in[4];
  const void* Wproj = d_in[5];
  const void* normw = d_in[6];
  const void* Wup = d_in[7];
  const void* Wgate = d_in[8];
  const void* Wdown = d_in[9];
  const void* predW = d_in[10];
  const void* predb = d_in[11];

  int* flagp = (int*)d_ws;
  float* base = (float*)d_ws + 64;               // 256B offset for flag slot
  const long NE = (long)BS_ * E_;                // 2097152
  float* emb   = base;
  float* hnorm = emb + NE;
  float* qb    = hnorm + NE;
  float* kb    = qb + NE;
  float* vb    = kb + NE;
  float* ob    = vb + NE;
  float* up    = ob + NE;
  float* gate  = up + (long)BS_ * F_;            // +8388608

  detect_kernel<<<dim3(1), dim3(64), 0, stream>>>((const unsigned*)normw, flagp);
  embed_kernel<<<dim3(BS_), dim3(256), 0, stream>>>(tokens, table, emb, flagp);

  for (int l = 0; l < L_; l++) {
    const long offQKV = (long)l * H_ * E_ * DK_;   // 1048576
    const long offP   = (long)l * E_ * E_;
    const long offN   = (long)l * E_;
    const long offUG  = (long)l * E_ * F_;
    const long offD   = (long)l * F_ * E_;

    // q,k,v: [2048,1024] x per-head [E,DK];  B addr = h*E*64 + e*64 + dk
    gemm_kernel<<<dim3(16, 32), dim3(256), 0, stream>>>(
        emb, Wq, qb, nullptr, nullptr, nullptr, flagp,
        BS_, H_ * DK_, E_, 0, offQKV, (long)E_ * DK_, 64, 1);
    gemm_kernel<<<dim3(16, 32), dim3(256), 0, stream>>>(
        emb, Wk, kb, nullptr, nullptr, nullptr, flagp,
        BS_, H_ * DK_, E_, 0, offQKV, (long)E_ * DK_, 64, 1);
    gemm_kernel<<<dim3(16, 32), dim3(256), 0, stream>>>(
        emb, Wv, vb, nullptr, nullptr, nullptr, flagp,
        BS_, H_ * DK_, E_, 0, offQKV, (long)E_ * DK_, 64, 1);

    rope_kernel<<<dim3(2 * B_ * H_ * S_), dim3(64), 0, stream>>>(qb, kb);
    attn_kernel<<<dim3(S_, B_ * H_), dim3(256), 0, stream>>>(qb, kb, vb, ob);

    // emb += o @ Wproj   (A gathered from bhsd)
    gemm_kernel<<<dim3(16, 32), dim3(256), 0, stream>>>(
        ob, Wproj, emb, emb, nullptr, nullptr, flagp,
        BS_, E_, E_, 1, offP, 64, E_, 0);

    rmsnorm_kernel<<<dim3(BS_), dim3(256), 0, stream>>>(emb, normw, hnorm, flagp, offN);

    // up = h @ Wup ; gate-buf = up * elu(h @ Wgate) ; emb += gate-buf @ Wdown
    gemm_kernel<<<dim3(64, 32), dim3(256), 0, stream>>>(
        hnorm, Wup, up, nullptr, nullptr, nullptr, flagp,
        BS_, F_, E_, 0, offUG, 64, F_, 0);
    gemm_kernel<<<dim3(64, 32), dim3(256), 0, stream>>>(
        hnorm, Wgate, gate, up, nullptr, nullptr, flagp,
        BS_, F_, E_, 0, offUG, 64, F_, 3);
    gemm_kernel<<<dim3(16, 32), dim3(256), 0, stream>>>(
        gate, Wdown, emb, emb, nullptr, nullptr, flagp,
        BS_, E_, F_, 0, offD, 64, E_, 0);
  }

  // logits = emb @ pred_W + pred_b  -> d_out (dtype per flag)
  gemm_kernel<<<dim3(V_ / 64, BS_ / 64), dim3(256), 0, stream>>>(
      emb, predW, nullptr, nullptr, predb, d_out, flagp,
      BS_, V_, E_, 0, 0, 64, V_, 2);
}